// Round 1
// baseline (214.801 us; speedup 1.0000x reference)
//
#include <hip/hip_runtime.h>

#define N2 128
#define MM 16384
#define START 6
#define TC 64        // threads per block == columns per block
#define PSTRIDE 132  // padded LDS row stride in floats (16B-aligned, +4 bank spread)

__global__ __launch_bounds__(TC) void npi_fused(
    const float* __restrict__ rt, const float* __restrict__ dgt,
    const float* __restrict__ si, const float* __restrict__ f,
    const float* __restrict__ seed, float* __restrict__ out)
{
    __shared__ __align__(16) float pred[TC * PSTRIDE];
    const int t = threadIdx.x;
    const int m = blockIdx.x * TC + t;
    float* my = &pred[t * PSTRIDE];

    // ---------------- Phase 1: cases recurrence ----------------
    // Block 0 (i0 = 0): seeds + in-register triangle.
    {
        float v[16];
#pragma unroll
        for (int k = 0; k < 16; ++k) {
            if (k < START) {
                v[k] = seed[k * MM + m];
            } else {
                float s = 0.f;
#pragma unroll
                for (int kk = 0; kk < 16; ++kk) {
                    if (kk < k) s += v[kk] * si[k - kk];
                }
                v[k] = rt[k * MM + m] * s;
            }
            my[k] = v[k];
        }
    }
    // Blocks i0 = 16..112: dense history part + in-register triangle.
    for (int i0 = 16; i0 < N2; i0 += 16) {
        float acc[16];
#pragma unroll
        for (int k = 0; k < 16; ++k) acc[k] = 0.f;
        for (int j = 0; j < i0; j += 4) {
            float4 p = *(const float4*)(my + j);
#pragma unroll
            for (int k = 0; k < 16; ++k) {
                acc[k] += p.x * si[i0 + k - j];
                acc[k] += p.y * si[i0 + k - j - 1];
                acc[k] += p.z * si[i0 + k - j - 2];
                acc[k] += p.w * si[i0 + k - j - 3];
            }
        }
        float v[16];
#pragma unroll
        for (int k = 0; k < 16; ++k) {
            float s = acc[k];
#pragma unroll
            for (int kk = 0; kk < 16; ++kk) {
                if (kk < k) s += v[kk] * si[k - kk];
            }
            v[k] = rt[(i0 + k) * MM + m] * s;
            my[i0 + k] = v[k];
        }
    }

    // ---------------- Phase 2: deaths conv + MSE ----------------
    float lsum;
    {
        float d0 = 1e-9f - dgt[0 * MM + m];
        lsum = d0 * d0;
#pragma unroll
        for (int i = 1; i < START; ++i) {
            float di = dgt[i * MM + m];
            lsum += di * di;
        }
    }

    for (int i0 = START; i0 < N2; i0 += 8) {
        float acc[8];
#pragma unroll
        for (int k = 0; k < 8; ++k) acc[k] = 0.f;

        const int J = (i0 - 1) & ~7;  // main region [0, J), all k active there
        // Prologue: j in [J, min(i0+5, 125)], per-k predicated (uniform conds).
        const int jend = (i0 + 5 < 125) ? (i0 + 5) : 125;
        for (int j = J; j <= jend; ++j) {
            float pv = my[j];
#pragma unroll
            for (int k = 0; k < 8; ++k) {
                int d = i0 + k - j;
                if (d >= 2 && (i0 + k) < N2)
                    acc[k] += pv * f[d * MM + m];
            }
        }

        // Main region: descending chunks of 8 j's, circular f-window in regs.
        if (J > 0) {
            float c[8];
            const int d0f = i0 - J + 1;  // window base at first chunk (>= 2)
#pragma unroll
            for (int k = 0; k < 8; ++k) c[k] = f[(d0f + k) * MM + m];
            for (int j8 = J - 8; j8 >= 0; j8 -= 8) {
                float4 lo = *(const float4*)(my + j8);
                float4 hi = *(const float4*)(my + j8 + 4);
                const int dbase = i0 - j8 - 7;
#pragma unroll
                for (int s = 0; s < 8; ++s) {
                    float myv = (s == 0) ? hi.w : (s == 1) ? hi.z : (s == 2) ? hi.y :
                                (s == 3) ? hi.x : (s == 4) ? lo.w : (s == 5) ? lo.z :
                                (s == 6) ? lo.y : lo.x;
#pragma unroll
                    for (int k = 0; k < 8; ++k)
                        acc[k] += myv * c[(s + k) & 7];
                    int dr = dbase + s + 8;
                    if (dr > N2 - 1) dr = N2 - 1;  // clamp (only matters on last tile; acc discarded)
                    c[s] = f[dr * MM + m];
                }
            }
        }

#pragma unroll
        for (int k = 0; k < 8; ++k) {
            int i = i0 + k;
            if (i < N2) {
                float diff = acc[k] - dgt[i * MM + m];
                lsum += diff * diff;
            }
        }
    }

    // Wave (== block) reduction, one atomic per block.
#pragma unroll
    for (int off = 32; off > 0; off >>= 1)
        lsum += __shfl_down(lsum, off, 64);
    if (t == 0)
        atomicAdd(out, lsum * (1.0f / ((float)N2 * (float)MM)));
}

extern "C" void kernel_launch(void* const* d_in, const int* in_sizes, int n_in,
                              void* d_out, int out_size, void* d_ws, size_t ws_size,
                              hipStream_t stream) {
    const float* rt   = (const float*)d_in[0];
    const float* dgt  = (const float*)d_in[1];
    const float* si   = (const float*)d_in[2];
    const float* f    = (const float*)d_in[3];
    const float* seed = (const float*)d_in[4];
    // d_in[5] is `start` (== 6), compiled in as START.

    hipMemsetAsync(d_out, 0, sizeof(float), stream);
    npi_fused<<<dim3(MM / TC), dim3(TC), 0, stream>>>(
        rt, dgt, si, f, seed, (float*)d_out);
}

// Round 2
// 109.506 us; speedup vs baseline: 1.9615x; 1.9615x over previous
//
#include <hip/hip_runtime.h>

#define N2 128
#define MM 16384
#define START 6
#define TC 64          // columns per block
#define W 8            // waves per block
#define BT (TC * W)    // 512 threads

// LDS budget = exactly 64 KiB:
//   predT[128][64]  (32 KiB)  time-major prediction
//   red  [8][16][64](32 KiB)  phase-1 partials (slots 0..6) / phase-2 fT[128][64]
//   si_s  = red tail [7168..7295]  (slot-7 region, unused by partials)
//   lred  = red tail [7296..7303]  (used only after a barrier past all fT reads)

__global__ __launch_bounds__(BT) void npi_fused(
    const float* __restrict__ rt, const float* __restrict__ dgt,
    const float* __restrict__ si, const float* __restrict__ f,
    const float* __restrict__ seed, float* __restrict__ out)
{
    __shared__ float predT[N2 * TC];
    __shared__ float red[8 * 16 * TC];
    float* si_s = &red[7 * 16 * TC];        // 128 floats
    float* lred = &red[7 * 16 * TC + N2];   // 8 floats

    const int t = threadIdx.x;
    const int c = t & 63;
    const int w = t >> 6;
    const int m = blockIdx.x * TC + c;

    if (t < N2) si_s[t] = si[t];
    __syncthreads();

    // SI[1..15] in registers (for the triangles); broadcast LDS reads.
    float sr[16];
#pragma unroll
    for (int k = 1; k < 16; ++k) sr[k] = si_s[k];

    // ---------------- Phase 1, step i0 = 0 (wave 7 only) ----------------
    if (w == 7) {
        float v[16];
#pragma unroll
        for (int k = 0; k < 16; ++k) {
            if (k < START) {
                v[k] = seed[k * MM + m];
            } else {
                float s = 0.f;
#pragma unroll
                for (int kk = 0; kk < 16; ++kk)
                    if (kk < k) s += v[kk] * sr[k - kk];
                v[k] = rt[k * MM + m] * s;
            }
            predT[k * TC + c] = v[k];
        }
    }
    __syncthreads();

    // ---------------- Phase 1, steps i0 = 16..112 ----------------
    for (int b = 1; b < 8; ++b) {
        const int i0 = b << 4;
        float r16[16];
        if (w == 7) {
            // prefetch rt for the triangle while others do history
#pragma unroll
            for (int k = 0; k < 16; ++k) r16[k] = rt[(i0 + k) * MM + m];
        } else if (w < b) {
            // history chunk j in [16w, 16w+16), descending; sliding SI window
            const int j0 = w << 4;
            const int D0 = i0 - j0 - 15;      // >= 1
            float c16[16];
#pragma unroll
            for (int e = 0; e < 16; ++e) c16[(e + 1) & 15] = si_s[D0 + e];
            float acc[16];
#pragma unroll
            for (int k = 0; k < 16; ++k) acc[k] = 0.f;
#pragma unroll
            for (int s = 0; s < 16; ++s) {
                float p = predT[((j0 + 15 - s) << 6) + c];
#pragma unroll
                for (int k = 0; k < 16; ++k)
                    acc[k] += p * c16[(s + k + 1) & 15];
                if (s < 15) c16[(s + 1) & 15] = si_s[D0 + 16 + s];
            }
#pragma unroll
            for (int k = 0; k < 16; ++k)
                red[(((w << 4) + k) << 6) + c] = acc[k];
        }
        __syncthreads();

        // distributed reduction: 16k x 64c sums -> predT rows i0..i0+15
#pragma unroll
        for (int e2 = 0; e2 < 2; ++e2) {
            int e = t + (e2 << 9);
            int k = e >> 6, c2 = e & 63;
            float tot = 0.f;
            for (int ww = 0; ww < b; ++ww)
                tot += red[(((ww << 4) + k) << 6) + c2];
            predT[((i0 + k) << 6) + c2] = tot;
        }
        __syncthreads();

        if (w == 7) {
            float v[16];
#pragma unroll
            for (int k = 0; k < 16; ++k) {
                float s = predT[((i0 + k) << 6) + c];
#pragma unroll
                for (int kk = 0; kk < 16; ++kk)
                    if (kk < k) s += v[kk] * sr[k - kk];
                v[k] = r16[k] * s;
                predT[((i0 + k) << 6) + c] = v[k];
            }
        }
        __syncthreads();
    }

    // ---------------- stage f into LDS (red becomes fT[128][64]) ----------------
#pragma unroll
    for (int q = 0; q < 16; ++q) {
        int d = w + (q << 3);                 // 0..127
        red[(d << 6) + c] = f[d * MM + m];
    }
    __syncthreads();

    // ---------------- Phase 2: deaths conv + MSE ----------------
    float lsum = 0.f;
    if (w == 0) {
        float d0 = 1e-9f - dgt[m];
        lsum = d0 * d0;
#pragma unroll
        for (int i = 1; i < START; ++i) {
            float di = dgt[i * MM + m];
            lsum += di * di;
        }
    }

#pragma unroll
    for (int half = 0; half < 2; ++half) {
        const int n = half ? (15 - w) : w;    // chunks {w, 15-w}: balanced
        const int i0 = START + (n << 3);
        float acc8[8];
#pragma unroll
        for (int k = 0; k < 8; ++k) acc8[k] = 0.f;

        const int J = (i0 - 1) & ~7;
        const int jend = (i0 + 5 < 125) ? (i0 + 5) : 125;
        for (int j = J; j <= jend; ++j) {
            float pv = predT[(j << 6) + c];
#pragma unroll
            for (int k = 0; k < 8; ++k) {
                int d = i0 + k - j;
                if (d >= 2 && (i0 + k) < N2)
                    acc8[k] += pv * red[(d << 6) + c];
            }
        }
        if (J > 0) {
            float c8[8];
            const int d0f = i0 - J + 1;       // >= 2
#pragma unroll
            for (int k = 0; k < 8; ++k) c8[k] = red[((d0f + k) << 6) + c];
            for (int j8 = J - 8; j8 >= 0; j8 -= 8) {
                const int dbase = i0 - j8 - 7;
#pragma unroll
                for (int s = 0; s < 8; ++s) {
                    float pv = predT[((j8 + 7 - s) << 6) + c];
#pragma unroll
                    for (int k = 0; k < 8; ++k)
                        acc8[k] += pv * c8[(s + k) & 7];
                    int dr = dbase + s + 8;
                    if (dr > N2 - 1) dr = N2 - 1;
                    c8[s] = red[(dr << 6) + c];
                }
            }
        }
#pragma unroll
        for (int k = 0; k < 8; ++k) {
            int i = i0 + k;
            if (i < N2) {
                float diff = acc8[k] - dgt[i * MM + m];
                lsum += diff * diff;
            }
        }
    }

    // ---------------- loss reduction ----------------
#pragma unroll
    for (int off = 32; off > 0; off >>= 1)
        lsum += __shfl_down(lsum, off, 64);
    __syncthreads();                          // all fT reads done before lred reuse
    if (c == 0) lred[w] = lsum;
    __syncthreads();
    if (t == 0) {
        float tot = 0.f;
#pragma unroll
        for (int ww = 0; ww < W; ++ww) tot += lred[ww];
        atomicAdd(out, tot * (1.0f / ((float)N2 * (float)MM)));
    }
}

extern "C" void kernel_launch(void* const* d_in, const int* in_sizes, int n_in,
                              void* d_out, int out_size, void* d_ws, size_t ws_size,
                              hipStream_t stream) {
    const float* rt   = (const float*)d_in[0];
    const float* dgt  = (const float*)d_in[1];
    const float* si   = (const float*)d_in[2];
    const float* f    = (const float*)d_in[3];
    const float* seed = (const float*)d_in[4];

    hipMemsetAsync(d_out, 0, sizeof(float), stream);
    npi_fused<<<dim3(MM / TC), dim3(BT), 0, stream>>>(
        rt, dgt, si, f, seed, (float*)d_out);
}